// Round 10
// baseline (2347.145 us; speedup 1.0000x reference)
//
#include <hip/hip_runtime.h>

// ---------------- problem constants ----------------
#define NN      20000     // nodes per type
#define EE      320000    // edges per relation
#define ETOT    340000    // EE + NN self loops
#define FD      512       // raw feature dim
#define HH_     4         // heads
#define CD      128       // channels per head
#define HHD     512       // H*C
#define BG      64        // batch graphs
#define INNERD  64

typedef __attribute__((ext_vector_type(8))) short bf16x8;
typedef __attribute__((ext_vector_type(4))) float f32x4;

// ---- bf16 <-> f32 via raw bits ----
__device__ __forceinline__ float bf2f(unsigned v) { return __uint_as_float(v << 16); }
__device__ __forceinline__ unsigned short f2bf(float f) {
    unsigned u = __float_as_uint(f);
    unsigned r = 0x7fffu + ((u >> 16) & 1u);
    return (unsigned short)((u + r) >> 16);
}
__device__ __forceinline__ void load8bf(const unsigned short* p, float* f) {
    uint4 u = *reinterpret_cast<const uint4*>(p);
    f[0] = bf2f(u.x & 0xffffu); f[1] = bf2f(u.x >> 16);
    f[2] = bf2f(u.y & 0xffffu); f[3] = bf2f(u.y >> 16);
    f[4] = bf2f(u.z & 0xffffu); f[5] = bf2f(u.z >> 16);
    f[6] = bf2f(u.w & 0xffffu); f[7] = bf2f(u.w >> 16);
}
// split f32 -> hi + lo bf16 (16 mantissa bits total)
__device__ __forceinline__ void split_f32(float x, unsigned short& hi, unsigned short& lo) {
    hi = f2bf(x);
    lo = f2bf(x - bf2f(hi));
}
template <typename TA>
__device__ __forceinline__ void splitA(const TA* p, size_t i, unsigned short& hi, unsigned short& lo);
template <>
__device__ __forceinline__ void splitA<float>(const float* p, size_t i, unsigned short& hi, unsigned short& lo) {
    split_f32(p[i], hi, lo);
}
template <>
__device__ __forceinline__ void splitA<unsigned short>(const unsigned short* p, size_t i, unsigned short& hi, unsigned short& lo) {
    hi = p[i]; lo = 0;
}

// ================= CSR build (per relation, rebuilt every call) =================
__global__ __launch_bounds__(256) void csr_hist(const int* __restrict__ ei, int* __restrict__ cnt) {
    int e = blockIdx.x * blockDim.x + threadIdx.x;
    if (e < EE) atomicAdd(&cnt[ei[EE + e]], 1);
}

__global__ __launch_bounds__(1024) void csr_scan(const int* __restrict__ cnt,
                                                 int* __restrict__ rowptr,
                                                 int* __restrict__ cursor) {
    __shared__ int part[1024];
    int t = threadIdx.x;
    int base = t * 20;
    int s = 0;
    #pragma unroll
    for (int i = 0; i < 20; ++i) { int n = base + i; if (n < NN) s += cnt[n] + 1; }
    part[t] = s;
    __syncthreads();
    for (int off = 1; off < 1024; off <<= 1) {
        int v = (t >= off) ? part[t - off] : 0;
        __syncthreads();
        part[t] += v;
        __syncthreads();
    }
    int run = (t > 0) ? part[t - 1] : 0;
    #pragma unroll
    for (int i = 0; i < 20; ++i) {
        int n = base + i;
        if (n < NN) { rowptr[n] = run; cursor[n] = run; run += cnt[n] + 1; }
    }
    if (t == 1023) rowptr[NN] = run;
}

__global__ __launch_bounds__(256) void csr_scatter(const int* __restrict__ ei,
                                                   int* __restrict__ cursor,
                                                   int* __restrict__ srcs) {
    int idx = blockIdx.x * blockDim.x + threadIdx.x;
    if (idx >= ETOT) return;
    int src, dst;
    if (idx < EE) { src = ei[idx]; dst = ei[EE + idx]; }
    else          { src = dst = idx - EE; }
    int pos = atomicAdd(&cursor[dst], 1);
    srcs[pos] = src;
}

// ================= split-bf16 MFMA GEMM (near-f32 precision) =================
// C[M,N](bf16) = A[M,K] @ B[K, N cols of ldb](f32). 64x64 tiles, 256 thr.
// D = Ah*Bh + Ah*Bl + (A_EXACT ? 0 : Al*Bh). blockIdx.z batches xl / xr sides.
template <typename TA, bool A_EXACT>
__global__ __launch_bounds__(256) void gemm_mfma(
    const TA* __restrict__ A0, const TA* __restrict__ A1,
    const float* __restrict__ B0, const float* __restrict__ B1, int ldb,
    unsigned short* __restrict__ C0, unsigned short* __restrict__ C1,
    int M, int K, int N)
{
    const TA* A = blockIdx.z ? A1 : A0;
    const float* B = blockIdx.z ? B1 : B0;
    unsigned short* C = blockIdx.z ? C1 : C0;

    __shared__ unsigned short Ah[64][40];   // [m][k] stride 80B; 16B-aligned segs
    __shared__ unsigned short Al[64][40];
    __shared__ unsigned short Bh[64][40];   // [n][k] (B transposed on store)
    __shared__ unsigned short Bl[64][40];
    const int tid = threadIdx.x;
    const int wave = tid >> 6, lane = tid & 63;
    const int quad = lane >> 4, lrow = lane & 15;
    const int tileM = blockIdx.y * 64, tileN = blockIdx.x * 64;
    const int wm = (wave >> 1) * 32, wn = (wave & 1) * 32;

    f32x4 acc[2][2] = {};

    const int am = tid >> 2;            // A loader: row (0..63)
    const int aks = (tid & 3) * 8;      // A loader: k-seg
    const int bn = tid & 63;            // B loader: col
    const int bk0 = (tid >> 6) * 8;     // B loader: k-seg

    for (int k0 = 0; k0 < K; k0 += 32) {
        {   // ---- stage A: 64 x 32, hi/lo split ----
            int gm = tileM + am;
            bf16x8 ph = {}, pl = {};
            if (gm < M) {
                #pragma unroll
                for (int j = 0; j < 8; ++j) {
                    unsigned short h, l;
                    splitA(A, (size_t)gm * K + k0 + aks + j, h, l);
                    ph[j] = (short)h; pl[j] = (short)l;
                }
            }
            *reinterpret_cast<bf16x8*>(&Ah[am][aks]) = ph;
            if (!A_EXACT) *reinterpret_cast<bf16x8*>(&Al[am][aks]) = pl;
        }
        {   // ---- stage B (transposed): Bs[n][k], hi/lo split ----
            bf16x8 ph, pl;
            #pragma unroll
            for (int j = 0; j < 8; ++j) {
                unsigned short h, l;
                split_f32(B[(size_t)(k0 + bk0 + j) * ldb + tileN + bn], h, l);
                ph[j] = (short)h; pl[j] = (short)l;
            }
            *reinterpret_cast<bf16x8*>(&Bh[bn][bk0]) = ph;
            *reinterpret_cast<bf16x8*>(&Bl[bn][bk0]) = pl;
        }
        __syncthreads();
        bf16x8 ah[2], al[2], bh[2], bl[2];
        #pragma unroll
        for (int mi = 0; mi < 2; ++mi) {
            ah[mi] = *reinterpret_cast<const bf16x8*>(&Ah[wm + mi * 16 + lrow][quad * 8]);
            if (!A_EXACT)
                al[mi] = *reinterpret_cast<const bf16x8*>(&Al[wm + mi * 16 + lrow][quad * 8]);
        }
        #pragma unroll
        for (int ni = 0; ni < 2; ++ni) {
            bh[ni] = *reinterpret_cast<const bf16x8*>(&Bh[wn + ni * 16 + lrow][quad * 8]);
            bl[ni] = *reinterpret_cast<const bf16x8*>(&Bl[wn + ni * 16 + lrow][quad * 8]);
        }
        #pragma unroll
        for (int mi = 0; mi < 2; ++mi)
            #pragma unroll
            for (int ni = 0; ni < 2; ++ni) {
                acc[mi][ni] = __builtin_amdgcn_mfma_f32_16x16x32_bf16(
                    ah[mi], bh[ni], acc[mi][ni], 0, 0, 0);
                acc[mi][ni] = __builtin_amdgcn_mfma_f32_16x16x32_bf16(
                    ah[mi], bl[ni], acc[mi][ni], 0, 0, 0);
                if (!A_EXACT)
                    acc[mi][ni] = __builtin_amdgcn_mfma_f32_16x16x32_bf16(
                        al[mi], bh[ni], acc[mi][ni], 0, 0, 0);
            }
        __syncthreads();
    }
    // ---- epilogue: C/D layout col=lane&15, row=quad*4+reg ----
    #pragma unroll
    for (int mi = 0; mi < 2; ++mi) {
        #pragma unroll
        for (int ni = 0; ni < 2; ++ni) {
            int gcol = tileN + wn + ni * 16 + lrow;
            #pragma unroll
            for (int r = 0; r < 4; ++r) {
                int grow = tileM + wm + mi * 16 + quad * 4 + r;
                if (grow < M)
                    C[(size_t)grow * N + gcol] = f2bf(acc[mi][ni][r]);
            }
        }
    }
}

// ================= THIN: fused GATv2 pass, one head (xl/xr [NN,128]) =================
__global__ __launch_bounds__(256) void fused_aggr1(
    const int* __restrict__ rowptr, const int* __restrict__ srcs,
    const unsigned short* __restrict__ xl, const unsigned short* __restrict__ xr,
    const float* __restrict__ att,
    float* __restrict__ acc, int add_in, int fin_mode,
    const float* __restrict__ bA, const float* __restrict__ bB,
    unsigned short* __restrict__ z,
    const int* __restrict__ batch, float* __restrict__ pool)
{
    int dst = (int)((blockIdx.x * (size_t)blockDim.x + threadIdx.x) >> 6);
    int lane = threadIdx.x & 63;
    if (dst >= NN) return;
    int beg = rowptr[dst], end = rowptr[dst + 1];

    unsigned ub = *reinterpret_cast<const unsigned*>(xr + (size_t)dst * CD + lane * 2);
    float br0 = bf2f(ub & 0xffffu), br1 = bf2f(ub >> 16);
    float ta0 = att[lane * 2], ta1 = att[lane * 2 + 1];

    float n0 = 0.f, n1 = 0.f, den = 0.f;
    for (int k = beg; k < end; ++k) {
        int src = srcs[k];
        unsigned ua = *reinterpret_cast<const unsigned*>(xl + (size_t)src * CD + lane * 2);
        float a0 = bf2f(ua & 0xffffu), a1 = bf2f(ua >> 16);
        float v0 = a0 + br0, v1 = a1 + br1;
        v0 = (v0 > 0.f) ? v0 : 0.2f * v0;
        v1 = (v1 > 0.f) ? v1 : 0.2f * v1;
        float d = v0 * ta0 + v1 * ta1;
        #pragma unroll
        for (int off = 1; off < 64; off <<= 1)
            d += __shfl_xor(d, off);
        float p = expf(d);
        n0 += p * a0; n1 += p * a1; den += p;
    }
    float o0 = n0 / den, o1 = n1 / den;
    size_t ai = (size_t)dst * CD + lane * 2;
    if (add_in) { o0 += acc[ai]; o1 += acc[ai + 1]; }
    if (fin_mode == 0) {
        acc[ai] = o0; acc[ai + 1] = o1;
    } else {
        int c0 = lane * 2;
        float bb0 = 0.f, bb1 = 0.f;
        #pragma unroll
        for (int h = 0; h < HH_; ++h) {
            bb0 += bA[h * CD + c0]     + bB[h * CD + c0];
            bb1 += bA[h * CD + c0 + 1] + bB[h * CD + c0 + 1];
        }
        o0 = tanhf(o0 + bb0);
        o1 = tanhf(o1 + bb1);
        if (fin_mode == 1) {
            z[ai] = f2bf(o0); z[ai + 1] = f2bf(o1);
        } else {
            int b = batch[dst];
            atomicAdd(&pool[(size_t)b * CD + c0],     o0);
            atomicAdd(&pool[(size_t)b * CD + c0 + 1], o1);
        }
    }
}

// ================= FAT: fused GATv2 pass, ALL 4 heads, 4-edge unrolled =================
// one 64-lane wave per dst; 16-lane group per head; lane holds 8 channels (16B gathers).
// 4 independent gather->reduce->exp chains in flight; no LDS, no syncs.
__global__ __launch_bounds__(256) void fused_aggr4u(
    const int* __restrict__ rowptr, const int* __restrict__ srcs,
    const unsigned short* __restrict__ xl, const unsigned short* __restrict__ xr,
    const float* __restrict__ att,          // [512] f32 this relation (all heads)
    float* __restrict__ acc, int add_in, int fin_mode,
    const float* __restrict__ bA, const float* __restrict__ bB,
    unsigned short* __restrict__ z,
    const int* __restrict__ batch, float* __restrict__ pool)
{
    int dst = (int)((blockIdx.x * (size_t)blockDim.x + threadIdx.x) >> 6);
    int lane = threadIdx.x & 63;
    if (dst >= NN) return;
    int beg = rowptr[dst], end = rowptr[dst + 1];

    float br[8], ta[8];
    load8bf(xr + (size_t)dst * HHD + lane * 8, br);
    #pragma unroll
    for (int j = 0; j < 8; ++j) ta[j] = att[lane * 8 + j];

    float n[8] = {}; float den = 0.f;
    int k = beg;
    for (; k + 4 <= end; k += 4) {
        int s0 = srcs[k], s1 = srcs[k + 1], s2 = srcs[k + 2], s3 = srcs[k + 3];
        float a0[8], a1[8], a2[8], a3[8];
        load8bf(xl + (size_t)s0 * HHD + lane * 8, a0);
        load8bf(xl + (size_t)s1 * HHD + lane * 8, a1);
        load8bf(xl + (size_t)s2 * HHD + lane * 8, a2);
        load8bf(xl + (size_t)s3 * HHD + lane * 8, a3);
        float d0 = 0.f, d1 = 0.f, d2 = 0.f, d3 = 0.f;
        #pragma unroll
        for (int j = 0; j < 8; ++j) {
            float v0 = a0[j] + br[j], v1 = a1[j] + br[j];
            float v2 = a2[j] + br[j], v3 = a3[j] + br[j];
            v0 = (v0 > 0.f) ? v0 : 0.2f * v0;
            v1 = (v1 > 0.f) ? v1 : 0.2f * v1;
            v2 = (v2 > 0.f) ? v2 : 0.2f * v2;
            v3 = (v3 > 0.f) ? v3 : 0.2f * v3;
            d0 += v0 * ta[j]; d1 += v1 * ta[j];
            d2 += v2 * ta[j]; d3 += v3 * ta[j];
        }
        #pragma unroll
        for (int off = 1; off < 16; off <<= 1) {
            d0 += __shfl_xor(d0, off); d1 += __shfl_xor(d1, off);
            d2 += __shfl_xor(d2, off); d3 += __shfl_xor(d3, off);
        }
        float p0 = expf(d0), p1 = expf(d1), p2 = expf(d2), p3 = expf(d3);
        den += (p0 + p1) + (p2 + p3);
        #pragma unroll
        for (int j = 0; j < 8; ++j)
            n[j] += (p0 * a0[j] + p1 * a1[j]) + (p2 * a2[j] + p3 * a3[j]);
    }
    for (; k < end; ++k) {
        int s0 = srcs[k];
        float a0[8];
        load8bf(xl + (size_t)s0 * HHD + lane * 8, a0);
        float d0 = 0.f;
        #pragma unroll
        for (int j = 0; j < 8; ++j) {
            float v = a0[j] + br[j];
            v = (v > 0.f) ? v : 0.2f * v;
            d0 += v * ta[j];
        }
        #pragma unroll
        for (int off = 1; off < 16; off <<= 1)
            d0 += __shfl_xor(d0, off);
        float p = expf(d0);
        den += p;
        #pragma unroll
        for (int j = 0; j < 8; ++j) n[j] += p * a0[j];
    }
    float inv = 1.f / den;
    float o[8];
    #pragma unroll
    for (int j = 0; j < 8; ++j) {
        o[j] = n[j] * inv;
        o[j] += __shfl_xor(o[j], 16);   // head-sum (once per dst)
        o[j] += __shfl_xor(o[j], 32);
    }
    if (lane < 16) {
        size_t ai = (size_t)dst * CD + lane * 8;
        if (add_in) {
            #pragma unroll
            for (int j = 0; j < 8; ++j) o[j] += acc[ai + j];
        }
        if (fin_mode == 0) {
            #pragma unroll
            for (int j = 0; j < 8; ++j) acc[ai + j] = o[j];
        } else {
            int c0 = lane * 8;
            #pragma unroll
            for (int j = 0; j < 8; ++j) {
                float bb = 0.f;
                #pragma unroll
                for (int h = 0; h < HH_; ++h)
                    bb += bA[h * CD + c0 + j] + bB[h * CD + c0 + j];
                o[j] = tanhf(o[j] + bb);
            }
            if (fin_mode == 1) {
                #pragma unroll
                for (int j = 0; j < 8; ++j) z[ai + j] = f2bf(o[j]);
            } else {
                int b = batch[dst];
                #pragma unroll
                for (int j = 0; j < 8; ++j)
                    atomicAdd(&pool[(size_t)b * CD + c0 + j], o[j]);
            }
        }
    }
}

// ================= head: tanh(pool), small GEMVs, sigmoid; f32 out =================
__global__ __launch_bounds__(128) void head_kernel(
    const float* __restrict__ pool_i, const float* __restrict__ pool_j,
    const float* __restrict__ W_out, const float* __restrict__ b_out,
    const float* __restrict__ W_i, const float* __restrict__ b_i,
    const float* __restrict__ W_j, const float* __restrict__ b_j,
    float* __restrict__ out)
{
    int b = blockIdx.x;
    int t = threadIdx.x;
    __shared__ float pi[CD], pj[CD];
    pi[t] = tanhf(pool_i[(size_t)b * CD + t]);
    pj[t] = tanhf(pool_j[(size_t)b * CD + t]);
    __syncthreads();
    if (t < INNERD) {
        float a = b_i[t];
        for (int c = 0; c < CD; ++c) a += pi[c] * W_i[c * INNERD + t];
        out[BG + (size_t)b * INNERD + t] = a;
    } else {
        int k = t - INNERD;
        float a = b_j[k];
        for (int c = 0; c < CD; ++c) a += pj[c] * W_j[c * INNERD + k];
        out[BG + BG * INNERD + (size_t)b * INNERD + k] = a;
    }
    if (t == 0) {
        float a = b_out[0];
        for (int c = 0; c < CD; ++c) a += (pi[c] + pj[c]) * W_out[c];
        out[b] = 1.f / (1.f + expf(-a));
    }
}

// ================= host-side drivers =================
struct Ws {
    unsigned short *xl, *xr, *z_i, *z_j;
    float* acc;
    int *rowptr, *cnt, *cursor, *srcs;
    float *pool_i, *pool_j;
};

static void build_csr(const int* ei, const Ws& w, hipStream_t stream) {
    hipMemsetAsync(w.cnt, 0, NN * sizeof(int), stream);
    csr_hist<<<(EE + 255) / 256, 256, 0, stream>>>(ei, w.cnt);
    csr_scan<<<1, 1024, 0, stream>>>(w.cnt, w.rowptr, w.cursor);
    csr_scatter<<<(ETOT + 255) / 256, 256, 0, stream>>>(ei, w.cursor, w.srcs);
}

// ---- THIN path: per-head passes (xl/xr [NN,128]) ----
template <typename TA, bool A_EXACT>
static void run_group_thin(const TA* srcA[2], const TA* dstA[2],
                           const int* eis[2], const int rids[2], int K,
                           const float* Wl, const float* Wr, const float* att,
                           const float* bias, int fin_mode,
                           unsigned short* zout, const int* batch, float* pool,
                           const Ws& w, hipStream_t stream)
{
    dim3 gg(2, (NN + 63) / 64, 2);
    const int ablocks = NN / 4;
    for (int q = 0; q < 2; ++q) {
        int r = rids[q];
        build_csr(eis[q], w, stream);
        for (int h = 0; h < HH_; ++h) {
            const float* WlS = Wl + (size_t)r * K * HHD + h * CD;
            const float* WrS = Wr + (size_t)r * K * HHD + h * CD;
            gemm_mfma<TA, A_EXACT><<<gg, 256, 0, stream>>>(
                srcA[q], dstA[q], WlS, WrS, HHD, w.xl, w.xr, NN, K, CD);
            int pass = q * HH_ + h;
            int fm = (pass == 2 * HH_ - 1) ? fin_mode : 0;
            fused_aggr1<<<ablocks, 256, 0, stream>>>(
                w.rowptr, w.srcs, w.xl, w.xr,
                att + (size_t)r * HHD + h * CD,
                w.acc, pass > 0 ? 1 : 0, fm,
                bias + (size_t)rids[0] * HHD, bias + (size_t)rids[1] * HHD,
                zout, batch, pool);
        }
    }
}

// ---- FAT path: all-heads passes (xl/xr [NN,512]) ----
template <typename TA, bool A_EXACT>
static void run_group_fat(const TA* srcA[2], const TA* dstA[2],
                          const int* eis[2], const int rids[2], int K,
                          const float* Wl, const float* Wr, const float* att,
                          const float* bias, int fin_mode,
                          unsigned short* zout, const int* batch, float* pool,
                          const Ws& w, hipStream_t stream)
{
    dim3 gg(HHD / 64, (NN + 63) / 64, 2);
    const int ablocks = NN / 4;   // 4 dst per block, 1 wave each
    for (int q = 0; q < 2; ++q) {
        int r = rids[q];
        build_csr(eis[q], w, stream);
        gemm_mfma<TA, A_EXACT><<<gg, 256, 0, stream>>>(
            srcA[q], dstA[q],
            Wl + (size_t)r * K * HHD, Wr + (size_t)r * K * HHD, HHD,
            w.xl, w.xr, NN, K, HHD);
        int fm = (q == 1) ? fin_mode : 0;
        fused_aggr4u<<<ablocks, 256, 0, stream>>>(
            w.rowptr, w.srcs, w.xl, w.xr,
            att + (size_t)r * HHD,
            w.acc, q > 0 ? 1 : 0, fm,
            bias + (size_t)rids[0] * HHD, bias + (size_t)rids[1] * HHD,
            zout, batch, pool);
    }
}

extern "C" void kernel_launch(void* const* d_in, const int* in_sizes, int n_in,
                              void* d_out, int out_size, void* d_ws, size_t ws_size,
                              hipStream_t stream)
{
    const float* x_i   = (const float*)d_in[0];
    const float* x_j   = (const float*)d_in[1];
    const int* ei_ii   = (const int*)d_in[2];
    const int* ei_jj   = (const int*)d_in[3];
    const int* ei_ij   = (const int*)d_in[4];
    const int* ei_ji   = (const int*)d_in[5];
    const int* batch_i = (const int*)d_in[6];
    const int* batch_j = (const int*)d_in[7];
    const float* Wl0   = (const float*)d_in[8];
    const float* Wr0   = (const float*)d_in[9];
    const float* att0  = (const float*)d_in[10];
    const float* b0    = (const float*)d_in[11];
    const float* Wl1   = (const float*)d_in[12];
    const float* Wr1   = (const float*)d_in[13];
    const float* att1  = (const float*)d_in[14];
    const float* b1    = (const float*)d_in[15];
    const float* W_out = (const float*)d_in[16];
    const float* b_out = (const float*)d_in[17];
    const float* W_i   = (const float*)d_in[18];
    const float* b_i   = (const float*)d_in[19];
    const float* W_j   = (const float*)d_in[20];
    const float* b_j   = (const float*)d_in[21];
    float* out = (float*)d_out;

    // FAT needs: xl,xr [NN,512]bf16 + acc [NN,128]f32 + z_i,z_j [NN,128]bf16 + CSR + pools
    const size_t FAT_BYTES = (size_t)NN * HHD * 2 * 2      // xl, xr
                           + (size_t)NN * CD * 4           // acc
                           + (size_t)NN * CD * 2 * 2       // z_i, z_j
                           + (size_t)(NN + 4) * 4          // rowptr
                           + (size_t)NN * 4 * 2            // cnt, cursor
                           + (size_t)ETOT * 4              // srcs
                           + (size_t)BG * CD * 4 * 2;      // pools   = 63,105,552
    const bool fat = (ws_size >= FAT_BYTES);

    Ws w;
    char* p = (char*)d_ws;
    size_t xbytes = fat ? (size_t)NN * HHD * 2 : (size_t)NN * CD * 2;
    w.xl     = (unsigned short*)p; p += xbytes;
    w.xr     = (unsigned short*)p; p += xbytes;
    w.acc    = (float*)p;          p += (size_t)NN * CD * 4;
    w.z_i    = (unsigned short*)p; p += (size_t)NN * CD * 2;
    w.z_j    = (unsigned short*)p; p += (size_t)NN * CD * 2;
    w.rowptr = (int*)p;            p += (size_t)(NN + 4) * 4;
    w.cnt    = (int*)p;            p += (size_t)NN * 4;
    w.cursor = (int*)p;            p += (size_t)NN * 4;
    w.srcs   = (int*)p;            p += (size_t)ETOT * 4;
    w.pool_i = (float*)p;          p += (size_t)BG * CD * 4;
    w.pool_j = (float*)p;          p += (size_t)BG * CD * 4;

    hipMemsetAsync(w.pool_i, 0, (size_t)BG * CD * sizeof(float), stream);
    hipMemsetAsync(w.pool_j, 0, (size_t)BG * CD * sizeof(float), stream);

    // relation groups:  i <- {rel0: ii, rel3: ji},  j <- {rel1: jj, rel2: ij}
    const float* srcA0_i[2] = { x_i, x_j };  const float* dstA0_i[2] = { x_i, x_i };
    const float* srcA0_j[2] = { x_j, x_i };  const float* dstA0_j[2] = { x_j, x_j };
    const int* eis_i[2] = { ei_ii, ei_ji };  const int rids_i[2] = { 0, 3 };
    const int* eis_j[2] = { ei_jj, ei_ij };  const int rids_j[2] = { 1, 2 };
    const unsigned short* srcA1_i[2] = { w.z_i, w.z_j };
    const unsigned short* dstA1_i[2] = { w.z_i, w.z_i };
    const unsigned short* srcA1_j[2] = { w.z_j, w.z_i };
    const unsigned short* dstA1_j[2] = { w.z_j, w.z_j };

    if (fat) {
        run_group_fat<float, false>(srcA0_i, dstA0_i, eis_i, rids_i, FD, Wl0, Wr0, att0, b0,
                                    1, w.z_i, nullptr, nullptr, w, stream);
        run_group_fat<float, false>(srcA0_j, dstA0_j, eis_j, rids_j, FD, Wl0, Wr0, att0, b0,
                                    1, w.z_j, nullptr, nullptr, w, stream);
        run_group_fat<unsigned short, true>(srcA1_i, dstA1_i, eis_i, rids_i, CD, Wl1, Wr1, att1, b1,
                                            2, nullptr, batch_i, w.pool_i, w, stream);
        run_group_fat<unsigned short, true>(srcA1_j, dstA1_j, eis_j, rids_j, CD, Wl1, Wr1, att1, b1,
                                            2, nullptr, batch_j, w.pool_j, w, stream);
    } else {
        run_group_thin<float, false>(srcA0_i, dstA0_i, eis_i, rids_i, FD, Wl0, Wr0, att0, b0,
                                     1, w.z_i, nullptr, nullptr, w, stream);
        run_group_thin<float, false>(srcA0_j, dstA0_j, eis_j, rids_j, FD, Wl0, Wr0, att0, b0,
                                     1, w.z_j, nullptr, nullptr, w, stream);
        run_group_thin<unsigned short, true>(srcA1_i, dstA1_i, eis_i, rids_i, CD, Wl1, Wr1, att1, b1,
                                             2, nullptr, batch_i, w.pool_i, w, stream);
        run_group_thin<unsigned short, true>(srcA1_j, dstA1_j, eis_j, rids_j, CD, Wl1, Wr1, att1, b1,
                                             2, nullptr, batch_j, w.pool_j, w, stream);
    }

    head_kernel<<<BG, 128, 0, stream>>>(w.pool_i, w.pool_j, W_out, b_out,
                                        W_i, b_i, W_j, b_j, out);
}

// Round 11
// 1929.292 us; speedup vs baseline: 1.2166x; 1.2166x over previous
//
#include <hip/hip_runtime.h>

// ---------------- problem constants ----------------
#define NN      20000     // nodes per type
#define EE      320000    // edges per relation
#define ETOT    340000    // EE + NN self loops
#define FD      512       // raw feature dim
#define HH_     4         // heads
#define CD      128       // channels per head
#define HHD     512       // H*C
#define BG      64        // batch graphs
#define INNERD  64

typedef __attribute__((ext_vector_type(8))) short bf16x8;
typedef __attribute__((ext_vector_type(4))) float f32x4;

// ---- bf16 <-> f32 via raw bits ----
__device__ __forceinline__ float bf2f(unsigned v) { return __uint_as_float(v << 16); }
__device__ __forceinline__ unsigned short f2bf(float f) {
    unsigned u = __float_as_uint(f);
    unsigned r = 0x7fffu + ((u >> 16) & 1u);
    return (unsigned short)((u + r) >> 16);
}
__device__ __forceinline__ void load8bf(const unsigned short* p, float* f) {
    uint4 u = *reinterpret_cast<const uint4*>(p);
    f[0] = bf2f(u.x & 0xffffu); f[1] = bf2f(u.x >> 16);
    f[2] = bf2f(u.y & 0xffffu); f[3] = bf2f(u.y >> 16);
    f[4] = bf2f(u.z & 0xffffu); f[5] = bf2f(u.z >> 16);
    f[6] = bf2f(u.w & 0xffffu); f[7] = bf2f(u.w >> 16);
}
// fast split f32 -> hi + lo bf16 (truncation; residual ~2^-16 relative)
__device__ __forceinline__ void split_f32(float x, unsigned short& hi, unsigned short& lo) {
    unsigned u = __float_as_uint(x);
    hi = (unsigned short)(u >> 16);
    float r = x - bf2f(hi);
    lo = (unsigned short)(__float_as_uint(r) >> 16);
}
template <typename TA>
__device__ __forceinline__ void splitA(const TA* p, size_t i, unsigned short& hi, unsigned short& lo);
template <>
__device__ __forceinline__ void splitA<float>(const float* p, size_t i, unsigned short& hi, unsigned short& lo) {
    split_f32(p[i], hi, lo);
}
template <>
__device__ __forceinline__ void splitA<unsigned short>(const unsigned short* p, size_t i, unsigned short& hi, unsigned short& lo) {
    hi = p[i]; lo = 0;
}

// ================= CSR build =================
__global__ __launch_bounds__(256) void csr_hist(const int* __restrict__ ei, int* __restrict__ cnt) {
    int e = blockIdx.x * blockDim.x + threadIdx.x;
    if (e < EE) atomicAdd(&cnt[ei[EE + e]], 1);
}

__global__ __launch_bounds__(1024) void csr_scan(const int* __restrict__ cnt,
                                                 int* __restrict__ rowptr,
                                                 int* __restrict__ cursor) {
    __shared__ int part[1024];
    int t = threadIdx.x;
    int base = t * 20;
    int s = 0;
    #pragma unroll
    for (int i = 0; i < 20; ++i) { int n = base + i; if (n < NN) s += cnt[n] + 1; }
    part[t] = s;
    __syncthreads();
    for (int off = 1; off < 1024; off <<= 1) {
        int v = (t >= off) ? part[t - off] : 0;
        __syncthreads();
        part[t] += v;
        __syncthreads();
    }
    int run = (t > 0) ? part[t - 1] : 0;
    #pragma unroll
    for (int i = 0; i < 20; ++i) {
        int n = base + i;
        if (n < NN) { rowptr[n] = run; cursor[n] = run; run += cnt[n] + 1; }
    }
    if (t == 1023) rowptr[NN] = run;
}

// scatter src ids as uint16 (node ids < 65536); self-loop appended per node
__global__ __launch_bounds__(256) void csr_scatter16(const int* __restrict__ ei,
                                                     int* __restrict__ cursor,
                                                     unsigned short* __restrict__ srcs) {
    int idx = blockIdx.x * blockDim.x + threadIdx.x;
    if (idx >= ETOT) return;
    int src, dst;
    if (idx < EE) { src = ei[idx]; dst = ei[EE + idx]; }
    else          { src = dst = idx - EE; }
    int pos = atomicAdd(&cursor[dst], 1);
    srcs[pos] = (unsigned short)src;
}

// ================= split-bf16 MFMA GEMM (near-f32 precision) =================
// C[M,N](bf16) = A[M,K] @ B[K, N cols of ldb](f32). 64x64 tiles, 256 thr.
// D = Ah*Bh + Ah*Bl + (A_EXACT ? 0 : Al*Bh). blockIdx.z batches xl / xr sides.
template <typename TA, bool A_EXACT>
__global__ __launch_bounds__(256) void gemm_mfma(
    const TA* __restrict__ A0, const TA* __restrict__ A1,
    const float* __restrict__ B0, const float* __restrict__ B1, int ldb,
    unsigned short* __restrict__ C0, unsigned short* __restrict__ C1,
    int M, int K, int N)
{
    const TA* A = blockIdx.z ? A1 : A0;
    const float* B = blockIdx.z ? B1 : B0;
    unsigned short* C = blockIdx.z ? C1 : C0;

    __shared__ unsigned short Ah[64][40];   // [m][k] stride 80B; 16B-aligned segs
    __shared__ unsigned short Al[64][40];
    __shared__ unsigned short Bh[64][40];   // [n][k] (B transposed on store)
    __shared__ unsigned short Bl[64][40];
    const int tid = threadIdx.x;
    const int wave = tid >> 6, lane = tid & 63;
    const int quad = lane >> 4, lrow = lane & 15;
    const int tileM = blockIdx.y * 64, tileN = blockIdx.x * 64;
    const int wm = (wave >> 1) * 32, wn = (wave & 1) * 32;

    f32x4 acc[2][2] = {};

    const int am = tid >> 2;            // A loader: row (0..63)
    const int aks = (tid & 3) * 8;      // A loader: k-seg
    const int bn = tid & 63;            // B loader: col
    const int bk0 = (tid >> 6) * 8;     // B loader: k-seg

    for (int k0 = 0; k0 < K; k0 += 32) {
        {   // ---- stage A: 64 x 32, hi/lo split ----
            int gm = tileM + am;
            bf16x8 ph = {}, pl = {};
            if (gm < M) {
                #pragma unroll
                for (int j = 0; j < 8; ++j) {
                    unsigned short h, l;
                    splitA(A, (size_t)gm * K + k0 + aks + j, h, l);
                    ph[j] = (short)h; pl[j] = (short)l;
                }
            }
            *reinterpret_cast<bf16x8*>(&Ah[am][aks]) = ph;
            if (!A_EXACT) *reinterpret_cast<bf16x8*>(&Al[am][aks]) = pl;
        }
        {   // ---- stage B (transposed): Bs[n][k], hi/lo split ----
            bf16x8 ph, pl;
            #pragma unroll
            for (int j = 0; j < 8; ++j) {
                unsigned short h, l;
                split_f32(B[(size_t)(k0 + bk0 + j) * ldb + tileN + bn], h, l);
                ph[j] = (short)h; pl[j] = (short)l;
            }
            *reinterpret_cast<bf16x8*>(&Bh[bn][bk0]) = ph;
            *reinterpret_cast<bf16x8*>(&Bl[bn][bk0]) = pl;
        }
        __syncthreads();
        bf16x8 ah[2], al[2], bh[2], bl[2];
        #pragma unroll
        for (int mi = 0; mi < 2; ++mi) {
            ah[mi] = *reinterpret_cast<const bf16x8*>(&Ah[wm + mi * 16 + lrow][quad * 8]);
            if (!A_EXACT)
                al[mi] = *reinterpret_cast<const bf16x8*>(&Al[wm + mi * 16 + lrow][quad * 8]);
        }
        #pragma unroll
        for (int ni = 0; ni < 2; ++ni) {
            bh[ni] = *reinterpret_cast<const bf16x8*>(&Bh[wn + ni * 16 + lrow][quad * 8]);
            bl[ni] = *reinterpret_cast<const bf16x8*>(&Bl[wn + ni * 16 + lrow][quad * 8]);
        }
        #pragma unroll
        for (int mi = 0; mi < 2; ++mi)
            #pragma unroll
            for (int ni = 0; ni < 2; ++ni) {
                acc[mi][ni] = __builtin_amdgcn_mfma_f32_16x16x32_bf16(
                    ah[mi], bh[ni], acc[mi][ni], 0, 0, 0);
                acc[mi][ni] = __builtin_amdgcn_mfma_f32_16x16x32_bf16(
                    ah[mi], bl[ni], acc[mi][ni], 0, 0, 0);
                if (!A_EXACT)
                    acc[mi][ni] = __builtin_amdgcn_mfma_f32_16x16x32_bf16(
                        al[mi], bh[ni], acc[mi][ni], 0, 0, 0);
            }
        __syncthreads();
    }
    // ---- epilogue: C/D layout col=lane&15, row=quad*4+reg ----
    #pragma unroll
    for (int mi = 0; mi < 2; ++mi) {
        #pragma unroll
        for (int ni = 0; ni < 2; ++ni) {
            int gcol = tileN + wn + ni * 16 + lrow;
            #pragma unroll
            for (int r = 0; r < 4; ++r) {
                int grow = tileM + wm + mi * 16 + quad * 4 + r;
                if (grow < M)
                    C[(size_t)grow * N + gcol] = f2bf(acc[mi][ni][r]);
            }
        }
    }
}

// ================= THIN: fused GATv2 pass, one head (xl/xr [NN,128]) =================
__global__ __launch_bounds__(256) void fused_aggr1(
    const int* __restrict__ rowptr, const unsigned short* __restrict__ srcs,
    const unsigned short* __restrict__ xl, const unsigned short* __restrict__ xr,
    const float* __restrict__ att,
    float* __restrict__ acc, int add_in, int fin_mode,
    const float* __restrict__ bA, const float* __restrict__ bB,
    unsigned short* __restrict__ z,
    const int* __restrict__ batch, float* __restrict__ pool)
{
    int dst = (int)((blockIdx.x * (size_t)blockDim.x + threadIdx.x) >> 6);
    int lane = threadIdx.x & 63;
    if (dst >= NN) return;
    int beg = rowptr[dst], end = rowptr[dst + 1];

    unsigned ub = *reinterpret_cast<const unsigned*>(xr + (size_t)dst * CD + lane * 2);
    float br0 = bf2f(ub & 0xffffu), br1 = bf2f(ub >> 16);
    float ta0 = att[lane * 2], ta1 = att[lane * 2 + 1];

    float n0 = 0.f, n1 = 0.f, den = 0.f;
    for (int k = beg; k < end; ++k) {
        int src = srcs[k];
        unsigned ua = *reinterpret_cast<const unsigned*>(xl + (size_t)src * CD + lane * 2);
        float a0 = bf2f(ua & 0xffffu), a1 = bf2f(ua >> 16);
        float v0 = a0 + br0, v1 = a1 + br1;
        v0 = (v0 > 0.f) ? v0 : 0.2f * v0;
        v1 = (v1 > 0.f) ? v1 : 0.2f * v1;
        float d = v0 * ta0 + v1 * ta1;
        #pragma unroll
        for (int off = 1; off < 64; off <<= 1)
            d += __shfl_xor(d, off);
        float p = expf(d);
        n0 += p * a0; n1 += p * a1; den += p;
    }
    float o0 = n0 / den, o1 = n1 / den;
    size_t ai = (size_t)dst * CD + lane * 2;
    if (add_in) { o0 += acc[ai]; o1 += acc[ai + 1]; }
    if (fin_mode == 0) {
        acc[ai] = o0; acc[ai + 1] = o1;
    } else {
        int c0 = lane * 2;
        float bb0 = 0.f, bb1 = 0.f;
        #pragma unroll
        for (int h = 0; h < HH_; ++h) {
            bb0 += bA[h * CD + c0]     + bB[h * CD + c0];
            bb1 += bA[h * CD + c0 + 1] + bB[h * CD + c0 + 1];
        }
        o0 = tanhf(o0 + bb0);
        o1 = tanhf(o1 + bb1);
        if (fin_mode == 1) {
            z[ai] = f2bf(o0); z[ai + 1] = f2bf(o1);
        } else {
            int b = batch[dst];
            atomicAdd(&pool[(size_t)b * CD + c0],     o0);
            atomicAdd(&pool[(size_t)b * CD + c0 + 1], o1);
        }
    }
}

// ================= FAT: fused GATv2 pass, ALL 4 heads (R7-proven structure) =========
// one 64-lane wave per dst; 16-lane group per head; lane holds 8 channels (16B gathers).
// Per-edge reduce: xor 1/2/4/8 only; head-sum xor16/32 once per dst. No LDS, no syncs.
__global__ __launch_bounds__(256) void fused_aggr4(
    const int* __restrict__ rowptr, const unsigned short* __restrict__ srcs,
    const unsigned short* __restrict__ xl, const unsigned short* __restrict__ xr,
    const float* __restrict__ att,          // [512] f32 this relation (all heads)
    float* __restrict__ acc, int add_in, int fin_mode,
    const float* __restrict__ bA, const float* __restrict__ bB,
    unsigned short* __restrict__ z,
    const int* __restrict__ batch, float* __restrict__ pool)
{
    int dst = (int)((blockIdx.x * (size_t)blockDim.x + threadIdx.x) >> 6);
    int lane = threadIdx.x & 63;
    if (dst >= NN) return;
    int beg = rowptr[dst], end = rowptr[dst + 1];

    float br[8], ta[8];
    load8bf(xr + (size_t)dst * HHD + lane * 8, br);
    #pragma unroll
    for (int j = 0; j < 8; ++j) ta[j] = att[lane * 8 + j];

    float n[8] = {}; float den = 0.f;
    for (int k = beg; k < end; ++k) {
        int src = srcs[k];
        float a[8];
        load8bf(xl + (size_t)src * HHD + lane * 8, a);
        float d = 0.f;
        #pragma unroll
        for (int j = 0; j < 8; ++j) {
            float v = a[j] + br[j];
            v = (v > 0.f) ? v : 0.2f * v;
            d += v * ta[j];
        }
        d += __shfl_xor(d, 1);
        d += __shfl_xor(d, 2);
        d += __shfl_xor(d, 4);
        d += __shfl_xor(d, 8);
        float p = expf(d);
        den += p;
        #pragma unroll
        for (int j = 0; j < 8; ++j) n[j] += p * a[j];
    }
    float inv = 1.f / den;
    float o[8];
    #pragma unroll
    for (int j = 0; j < 8; ++j) {
        o[j] = n[j] * inv;
        o[j] += __shfl_xor(o[j], 16);   // head-sum (once per dst)
        o[j] += __shfl_xor(o[j], 32);
    }
    if (lane < 16) {
        size_t ai = (size_t)dst * CD + lane * 8;
        if (add_in) {
            #pragma unroll
            for (int j = 0; j < 8; ++j) o[j] += acc[ai + j];
        }
        if (fin_mode == 0) {
            #pragma unroll
            for (int j = 0; j < 8; ++j) acc[ai + j] = o[j];
        } else {
            int c0 = lane * 8;
            #pragma unroll
            for (int j = 0; j < 8; ++j) {
                float bb = 0.f;
                #pragma unroll
                for (int h = 0; h < HH_; ++h)
                    bb += bA[h * CD + c0 + j] + bB[h * CD + c0 + j];
                o[j] = tanhf(o[j] + bb);
            }
            if (fin_mode == 1) {
                #pragma unroll
                for (int j = 0; j < 8; ++j) z[ai + j] = f2bf(o[j]);
            } else {
                int b = batch[dst];
                #pragma unroll
                for (int j = 0; j < 8; ++j)
                    atomicAdd(&pool[(size_t)b * CD + c0 + j], o[j]);
            }
        }
    }
}

// ================= head: tanh(pool), small GEMVs, sigmoid; f32 out =================
__global__ __launch_bounds__(128) void head_kernel(
    const float* __restrict__ pool_i, const float* __restrict__ pool_j,
    const float* __restrict__ W_out, const float* __restrict__ b_out,
    const float* __restrict__ W_i, const float* __restrict__ b_i,
    const float* __restrict__ W_j, const float* __restrict__ b_j,
    float* __restrict__ out)
{
    int b = blockIdx.x;
    int t = threadIdx.x;
    __shared__ float pi[CD], pj[CD];
    pi[t] = tanhf(pool_i[(size_t)b * CD + t]);
    pj[t] = tanhf(pool_j[(size_t)b * CD + t]);
    __syncthreads();
    if (t < INNERD) {
        float a = b_i[t];
        for (int c = 0; c < CD; ++c) a += pi[c] * W_i[c * INNERD + t];
        out[BG + (size_t)b * INNERD + t] = a;
    } else {
        int k = t - INNERD;
        float a = b_j[k];
        for (int c = 0; c < CD; ++c) a += pj[c] * W_j[c * INNERD + k];
        out[BG + BG * INNERD + (size_t)b * INNERD + k] = a;
    }
    if (t == 0) {
        float a = b_out[0];
        for (int c = 0; c < CD; ++c) a += (pi[c] + pj[c]) * W_out[c];
        out[b] = 1.f / (1.f + expf(-a));
    }
}

// ================= host-side drivers =================
struct Ws {
    unsigned short *xl, *xr, *z_i, *z_j;
    float* acc;
    int *rowptr[4];                // per-relation rowptr (FAT2) or slot 0 only
    unsigned short *srcs[4];
    int *cnt, *cursor;
    float *pool_i, *pool_j;
};

static void build_csr(const int* ei, int* rowptr, unsigned short* srcs,
                      int* cnt, int* cursor, hipStream_t stream) {
    hipMemsetAsync(cnt, 0, NN * sizeof(int), stream);
    csr_hist<<<(EE + 255) / 256, 256, 0, stream>>>(ei, cnt);
    csr_scan<<<1, 1024, 0, stream>>>(cnt, rowptr, cursor);
    csr_scatter16<<<(ETOT + 255) / 256, 256, 0, stream>>>(ei, cursor, srcs);
}

// ---- FAT group pass: CSR slots provided (prebuilt); all-heads aggr ----
template <typename TA, bool A_EXACT>
static void run_group_fat(const TA* srcA[2], const TA* dstA[2],
                          const int* rp[2], const unsigned short* sr[2],
                          const int rids[2], int K,
                          const float* Wl, const float* Wr, const float* att,
                          const float* bias, int fin_mode,
                          unsigned short* zout, const int* batch, float* pool,
                          const Ws& w, hipStream_t stream)
{
    dim3 gg(HHD / 64, (NN + 63) / 64, 2);
    const int ablocks = NN / 4;   // 4 dst per block, 1 wave each (R7-proven)
    for (int q = 0; q < 2; ++q) {
        int r = rids[q];
        gemm_mfma<TA, A_EXACT><<<gg, 256, 0, stream>>>(
            srcA[q], dstA[q],
            Wl + (size_t)r * K * HHD, Wr + (size_t)r * K * HHD, HHD,
            w.xl, w.xr, NN, K, HHD);
        int fm = (q == 1) ? fin_mode : 0;
        fused_aggr4<<<ablocks, 256, 0, stream>>>(
            rp[q], sr[q], w.xl, w.xr,
            att + (size_t)r * HHD,
            w.acc, q > 0 ? 1 : 0, fm,
            bias + (size_t)rids[0] * HHD, bias + (size_t)rids[1] * HHD,
            zout, batch, pool);
    }
}

// ---- THIN group pass: per-head, rebuilds CSR slot 0 per relation ----
template <typename TA, bool A_EXACT>
static void run_group_thin(const TA* srcA[2], const TA* dstA[2],
                           const int* eis[2], const int rids[2], int K,
                           const float* Wl, const float* Wr, const float* att,
                           const float* bias, int fin_mode,
                           unsigned short* zout, const int* batch, float* pool,
                           const Ws& w, hipStream_t stream)
{
    dim3 gg(2, (NN + 63) / 64, 2);
    const int ablocks = NN / 4;
    for (int q = 0; q < 2; ++q) {
        int r = rids[q];
        build_csr(eis[q], w.rowptr[0], w.srcs[0], w.cnt, w.cursor, stream);
        for (int h = 0; h < HH_; ++h) {
            const float* WlS = Wl + (size_t)r * K * HHD + h * CD;
            const float* WrS = Wr + (size_t)r * K * HHD + h * CD;
            gemm_mfma<TA, A_EXACT><<<gg, 256, 0, stream>>>(
                srcA[q], dstA[q], WlS, WrS, HHD, w.xl, w.xr, NN, K, CD);
            int pass = q * HH_ + h;
            int fm = (pass == 2 * HH_ - 1) ? fin_mode : 0;
            fused_aggr1<<<ablocks, 256, 0, stream>>>(
                w.rowptr[0], w.srcs[0], w.xl, w.xr,
                att + (size_t)r * HHD + h * CD,
                w.acc, pass > 0 ? 1 : 0, fm,
                bias + (size_t)rids[0] * HHD, bias + (size_t)rids[1] * HHD,
                zout, batch, pool);
        }
    }
}

extern "C" void kernel_launch(void* const* d_in, const int* in_sizes, int n_in,
                              void* d_out, int out_size, void* d_ws, size_t ws_size,
                              hipStream_t stream)
{
    const float* x_i   = (const float*)d_in[0];
    const float* x_j   = (const float*)d_in[1];
    const int* ei_ii   = (const int*)d_in[2];
    const int* ei_jj   = (const int*)d_in[3];
    const int* ei_ij   = (const int*)d_in[4];
    const int* ei_ji   = (const int*)d_in[5];
    const int* batch_i = (const int*)d_in[6];
    const int* batch_j = (const int*)d_in[7];
    const float* Wl0   = (const float*)d_in[8];
    const float* Wr0   = (const float*)d_in[9];
    const float* att0  = (const float*)d_in[10];
    const float* b0    = (const float*)d_in[11];
    const float* Wl1   = (const float*)d_in[12];
    const float* Wr1   = (const float*)d_in[13];
    const float* att1  = (const float*)d_in[14];
    const float* b1    = (const float*)d_in[15];
    const float* W_out = (const float*)d_in[16];
    const float* b_out = (const float*)d_in[17];
    const float* W_i   = (const float*)d_in[18];
    const float* b_i   = (const float*)d_in[19];
    const float* W_j   = (const float*)d_in[20];
    const float* b_j   = (const float*)d_in[21];
    float* out = (float*)d_out;

    // FAT2: 4 prebuilt CSRs (uint16 srcs). 40.96 + 10.24 + 10.24 + 2.72 + 0.32 + 0.16 + 0.065 = 64.71 MB
    const size_t FAT2_BYTES = (size_t)NN * HHD * 2 * 2 + (size_t)NN * CD * 4
                            + (size_t)NN * CD * 2 * 2 + 4 * (size_t)ETOT * 2
                            + 4 * (size_t)(NN + 4) * 4 + (size_t)NN * 4 * 2
                            + (size_t)BG * CD * 4 * 2;
    // FAT1: 1 CSR slot rebuilt per relation-group (R7-equivalent, smaller)
    const size_t FAT1_BYTES = (size_t)NN * HHD * 2 * 2 + (size_t)NN * CD * 4
                            + (size_t)NN * CD * 2 * 2 + (size_t)ETOT * 2
                            + (size_t)(NN + 4) * 4 + (size_t)NN * 4 * 2
                            + (size_t)BG * CD * 4 * 2;
    const int ncsr = (ws_size >= FAT2_BYTES) ? 4 : 1;
    const bool fat = (ws_size >= FAT1_BYTES);

    Ws w;
    char* p = (char*)d_ws;
    size_t xbytes = fat ? (size_t)NN * HHD * 2 : (size_t)NN * CD * 2;
    w.xl     = (unsigned short*)p; p += xbytes;
    w.xr     = (unsigned short*)p; p += xbytes;
    w.acc    = (float*)p;          p += (size_t)NN * CD * 4;
    w.z_i    = (unsigned short*)p; p += (size_t)NN * CD * 2;
    w.z_j    = (unsigned short*)p; p += (size_t)NN * CD * 2;
    for (int r = 0; r < 4; ++r) {
        int rr = (r < ncsr) ? r : 0;
        if (r < ncsr) {
            w.rowptr[r] = (int*)p;            p += (size_t)(NN + 4) * 4;
            w.srcs[r]   = (unsigned short*)p; p += (size_t)ETOT * 2;
        } else {
            w.rowptr[r] = w.rowptr[rr]; w.srcs[r] = w.srcs[rr];
        }
    }
    w.cnt    = (int*)p;            p += (size_t)NN * 4;
    w.cursor = (int*)p;            p += (size_t)NN * 4;
    w.pool_i = (float*)p;          p += (size_t)BG * CD * 4;
    w.pool_j = (float*)p;          p += (size_t)BG * CD * 4;

    hipMemsetAsync(w.pool_i, 0, (size_t)BG * CD * sizeof(float), stream);
    hipMemsetAsync(w.pool_j, 0, (size_t)BG * CD * sizeof(float), stream);

    // relation ids: 0=ii, 1=jj, 2=ij, 3=ji
    const int* eis_all[4] = { ei_ii, ei_jj, ei_ij, ei_ji };
    const float* srcA0_i[2] = { x_i, x_j };  const float* dstA0_i[2] = { x_i, x_i };
    const float* srcA0_j[2] = { x_j, x_i };  const float* dstA0_j[2] = { x_j, x_j };
    const int rids_i[2] = { 0, 3 };
    const int rids_j[2] = { 1, 2 };
    const unsigned short* srcA1_i[2] = { w.z_i, w.z_j };
    const unsigned short* dstA1_i[2] = { w.z_i, w.z_i };
    const unsigned short* srcA1_j[2] = { w.z_j, w.z_i };
    const unsigned short* dstA1_j[2] = { w.z_j, w.z_j };

    if (fat) {
        if (ncsr == 4) {
            // build all 4 CSRs once, reuse across both layers
            for (int r = 0; r < 4; ++r)
                build_csr(eis_all[r], w.rowptr[r], w.srcs[r], w.cnt, w.cursor, stream);
            const int* rp_i[2] = { w.rowptr[0], w.rowptr[3] };
            const unsigned short* sr_i[2] = { w.srcs[0], w.srcs[3] };
            const int* rp_j[2] = { w.rowptr[1], w.rowptr[2] };
            const unsigned short* sr_j[2] = { w.srcs[1], w.srcs[2] };
            run_group_fat<float, false>(srcA0_i, dstA0_i, rp_i, sr_i, rids_i, FD,
                                        Wl0, Wr0, att0, b0, 1, w.z_i, nullptr, nullptr, w, stream);
            run_group_fat<float, false>(srcA0_j, dstA0_j, rp_j, sr_j, rids_j, FD,
                                        Wl0, Wr0, att0, b0, 1, w.z_j, nullptr, nullptr, w, stream);
            run_group_fat<unsigned short, true>(srcA1_i, dstA1_i, rp_i, sr_i, rids_i, CD,
                                                Wl1, Wr1, att1, b1, 2, nullptr, batch_i, w.pool_i, w, stream);
            run_group_fat<unsigned short, true>(srcA1_j, dstA1_j, rp_j, sr_j, rids_j, CD,
                                                Wl1, Wr1, att1, b1, 2, nullptr, batch_j, w.pool_j, w, stream);
        } else {
            // 1 CSR slot: rebuild per relation (8 builds) — R7-equivalent
            const int* rp1[2] = { w.rowptr[0], w.rowptr[0] };
            const unsigned short* sr1[2] = { w.srcs[0], w.srcs[0] };
            struct GRP { const void* s[2]; const void* d[2]; const int* r[2]; };
            // layer 0 group i
            for (int pass = 0; pass < 4; ++pass) {
                // pass 0: L0 gi; 1: L0 gj; 2: L1 gi; 3: L1 gj
                const int* rids = (pass & 1) ? rids_j : rids_i;
                for (int q = 0; q < 2; ++q) {
                    int r = rids[q];
                    build_csr(eis_all[r], w.rowptr[0], w.srcs[0], w.cnt, w.cursor, stream);
                    dim3 gg(HHD / 64, (NN + 63) / 64, 2);
                    if (pass < 2) {
                        const float* sa = (pass == 0) ? srcA0_i[q] : srcA0_j[q];
                        const float* da = (pass == 0) ? dstA0_i[q] : dstA0_j[q];
                        gemm_mfma<float, false><<<gg, 256, 0, stream>>>(
                            sa, da, Wl0 + (size_t)r * FD * HHD, Wr0 + (size_t)r * FD * HHD,
                            HHD, w.xl, w.xr, NN, FD, HHD);
                        fused_aggr4<<<NN / 4, 256, 0, stream>>>(
                            w.rowptr[0], w.srcs[0], w.xl, w.xr, att0 + (size_t)r * HHD,
                            w.acc, q, (q == 1) ? 1 : 0,
                            b0 + (size_t)rids[0] * HHD, b0 + (size_t)rids[1] * HHD,
                            (pass == 0) ? w.z_i : w.z_j, nullptr, nullptr);
                    } else {
                        const unsigned short* sa = (pass == 2) ? srcA1_i[q] : srcA1_j[q];
                        const unsigned short* da = (pass == 2) ? dstA1_i[q] : dstA1_j[q];
                        gemm_mfma<unsigned short, true><<<gg, 256, 0, stream>>>(
                            sa, da, Wl1 + (size_t)r * CD * HHD, Wr1 + (size_t)r * CD * HHD,
                            HHD, w.xl, w.xr, NN, CD, HHD);
                        fused_aggr4<<<NN / 4, 256, 0, stream>>>(
                            w.rowptr[0], w.srcs[0], w.xl, w.xr, att1 + (size_t)r * HHD,
                            w.acc, q, (q == 1) ? 2 : 0,
                            b1 + (size_t)rids[0] * HHD, b1 + (size_t)rids[1] * HHD,
                            nullptr, (pass == 2) ? batch_i : batch_j,
                            (pass == 2) ? w.pool_i : w.pool_j);
                    }
                }
            }
        }
    } else {
        const int* eis_i[2] = { ei_ii, ei_ji };
        const int* eis_j[2] = { ei_jj, ei_ij };
        run_group_thin<float, false>(srcA0_i, dstA0_i, eis_i, rids_i, FD, Wl0, Wr0, att0, b0,
                                     1, w.z_i, nullptr, nullptr, w, stream);
        run_group_thin<float, false>(srcA0_j, dstA0_j, eis_j, rids_j, FD, Wl0, Wr0, att0, b0,
                                     1, w.z_j, nullptr, nullptr, w, stream);
        run_group_thin<unsigned short, true>(srcA1_i, dstA1_i, eis_i, rids_i, CD, Wl1, Wr1, att1, b1,
                                             2, nullptr, batch_i, w.pool_i, w, stream);
        run_group_thin<unsigned short, true>(srcA1_j, dstA1_j, eis_j, rids_j, CD, Wl1, Wr1, att1, b1,
                                             2, nullptr, batch_j, w.pool_j, w, stream);
    }

    head_kernel<<<BG, 128, 0, stream>>>(w.pool_i, w.pool_j, W_out, b_out,
                                        W_i, b_i, W_j, b_j, out);
}